// Round 4
// baseline (7684.927 us; speedup 1.0000x reference)
//
#include <hip/hip_runtime.h>
#include <hip/hip_bf16.h>
#include <math.h>

// ViT + BiFormer forward. f32 I/O. GEMMs: split-bf16 (hi+lo) triple-MFMA with
// 16B global_load_lds staging into packed hi/lo-interleaved LDS (stride 144B).
// Routing kept f32-exact. B=16, 197 tok, C=768, 12 heads, 12 layers, R=13, top-4.

typedef __bf16 bf16_t;
typedef __bf16 bf16x8 __attribute__((ext_vector_type(8)));
typedef float floatx4 __attribute__((ext_vector_type(4)));

static __device__ __forceinline__ float b2f(bf16_t x) { return (float)x; }
static __device__ __forceinline__ bf16_t f2b(float x) { return (bf16_t)x; }

// packed hi/lo layout: for matrix with K inner elements, row r, element k:
//   hi at r*2K + (k>>3)*16 + (k&7), lo at +8   (16B hi chunk, 16B lo chunk alternating)
static __device__ __forceinline__ size_t pk(int row, int k, int K) {
    return (size_t)row * (2 * K) + (size_t)((k >> 3) << 4) + (k & 7);
}

#define GLD(gp, lp)                                                                       \
    __builtin_amdgcn_global_load_lds((const __attribute__((address_space(1))) uint32_t*)(gp), \
                                     (__attribute__((address_space(3))) uint32_t*)(lp), 16, 0, 0)

// ---------------- transpose + split to packed: f32 [R,C] -> packed bf16 [C][2R] ---
__global__ void transpose_split_packed(const float* __restrict__ in, bf16_t* __restrict__ out,
                                       int R, int C, size_t inLs, size_t outLs) {
    const float* src = in + inLs * blockIdx.z;
    bf16_t* dst = out + outLs * blockIdx.z;
    __shared__ float tile[32][33];
    int c0 = blockIdx.x * 32, r0 = blockIdx.y * 32;
    int tx = threadIdx.x, ty = threadIdx.y;  // (32,8)
#pragma unroll
    for (int i = 0; i < 4; i++) {
        int r = r0 + ty + i * 8;
        float v = 0.f;
        if (r < R && (c0 + tx) < C) v = src[(size_t)r * C + c0 + tx];
        tile[ty + i * 8][tx] = v;
    }
    __syncthreads();
#pragma unroll
    for (int i = 0; i < 4; i++) {
        int c = c0 + ty + i * 8;
        int r = r0 + tx;
        if (c < C && r < R) {
            float v = tile[tx][ty + i * 8];
            bf16_t h = f2b(v);
            size_t o = pk(c, r, R);
            dst[o] = h;
            dst[o + 8] = f2b(v - b2f(h));
        }
    }
}

// ---------------- flat split to packed (conv_w already [N=768, K=768]) ----------
__global__ void split_packed(const float* __restrict__ in, bf16_t* __restrict__ out,
                             int N, int K) {
    int id = blockIdx.x * 256 + threadIdx.x;
    if (id >= N * K) return;
    int r = id / K, k = id % K;
    float v = in[id];
    bf16_t h = f2b(v);
    size_t o = pk(r, k, K);
    out[o] = h;
    out[o + 8] = f2b(v - b2f(h));
}

// ---------------- im2col (16x16/stride16) to packed ----------------
__global__ void im2col_packed(const float* __restrict__ x, bf16_t* __restrict__ out) {
    int id = blockIdx.x * 256 + threadIdx.x;
    if (id >= 3136 * 768) return;
    int col = id % 768, row = id / 768;
    int b = row / 196, p = row % 196;
    int py = p / 14, px = p % 14;
    int c = col >> 8, rem = col & 255, ky = rem >> 4, kx = rem & 15;
    float v = x[(((size_t)(b * 3 + c)) * 224 + (py * 16 + ky)) * 224 + (px * 16 + kx)];
    bf16_t h = f2b(v);
    size_t o = pk(row, col, 768);
    out[o] = h;
    out[o + 8] = f2b(v - b2f(h));
}

// ---------------- cls token + pos_embed row 0 ----------------
__global__ void clspos_kernel(const float* __restrict__ cls, const float* __restrict__ pos,
                              float* __restrict__ t) {
    int id = blockIdx.x * 256 + threadIdx.x;  // 16*768
    int b = id / 768, c = id % 768;
    t[((size_t)(b * 197)) * 768 + c] = cls[c] + pos[c];
}

// ---------------- LayerNorm: f32 in -> packed hi/lo out (+ optional f32) --------
__global__ __launch_bounds__(256) void ln_kernel(const float* __restrict__ in,
                                                 const float* __restrict__ g,
                                                 const float* __restrict__ bb,
                                                 bf16_t* __restrict__ op,
                                                 float* __restrict__ outf) {
    int row = blockIdx.x;
    int t = threadIdx.x;
    const float* x = in + (size_t)row * 768;
    float v0 = x[t], v1 = x[t + 256], v2 = x[t + 512];
    float s = v0 + v1 + v2;
#pragma unroll
    for (int off = 32; off > 0; off >>= 1) s += __shfl_down(s, off, 64);
    __shared__ float red[8];
    int lane = t & 63, wave = t >> 6;
    if (lane == 0) red[wave] = s;
    __syncthreads();
    float mu = (red[0] + red[1] + red[2] + red[3]) * (1.f / 768.f);
    float d0 = v0 - mu, d1 = v1 - mu, d2 = v2 - mu;
    float vs = d0 * d0 + d1 * d1 + d2 * d2;
#pragma unroll
    for (int off = 32; off > 0; off >>= 1) vs += __shfl_down(vs, off, 64);
    if (lane == 0) red[4 + wave] = vs;
    __syncthreads();
    float var = (red[4] + red[5] + red[6] + red[7]) * (1.f / 768.f);
    float rstd = 1.0f / sqrtf(var + 1e-5f);
    float y0 = d0 * rstd * g[t] + bb[t];
    float y1 = d1 * rstd * g[t + 256] + bb[t + 256];
    float y2 = d2 * rstd * g[t + 512] + bb[t + 512];
    bf16_t h0 = f2b(y0), h1 = f2b(y1), h2 = f2b(y2);
    size_t o0 = pk(row, t, 768), o1 = pk(row, t + 256, 768), o2 = pk(row, t + 512, 768);
    op[o0] = h0; op[o0 + 8] = f2b(y0 - b2f(h0));
    op[o1] = h1; op[o1 + 8] = f2b(y1 - b2f(h1));
    op[o2] = h2; op[o2 + 8] = f2b(y2 - b2f(h2));
    if (outf) {
        size_t base = (size_t)row * 768;
        outf[base + t] = y0; outf[base + t + 256] = y1; outf[base + t + 512] = y2;
    }
}

// ------- split-bf16 GEMM, packed operands, global_load_lds staging ---------------
// A packed [M][2K] bf16, B packed [N][2K] bf16. 3 MFMAs: AhBh + AhBl + AlBh.
// mode 1: outF = v    mode 2: outP = packed hi/lo(gelu(v))    mode 3: outF += v
// mode 4: embed: t[b*197+1+p][n] = v + pos[(1+p)*768+n], m = b*196+p
__global__ __launch_bounds__(256) void gemm_nts(const bf16_t* __restrict__ Apk,
                                                const bf16_t* __restrict__ Bpk,
                                                const float* __restrict__ bias,
                                                float* __restrict__ outF,
                                                bf16_t* __restrict__ outP,
                                                const float* __restrict__ pos,
                                                int M, int N, int K, int mode) {
    // LDS: 128 rows x 144B (8 chunks data + 1 pad chunk). 2 buffers = 36864B.
    __shared__ __align__(16) bf16_t As[128 * 72];
    __shared__ __align__(16) bf16_t Bs[128 * 72];
    const int t = threadIdx.x;
    const int lane = t & 63, wave = t >> 6;
    const int quad = lane >> 4, l16 = lane & 15;
    const int wm = (wave >> 1) * 64, wn = (wave & 1) * 64;
    const int m0 = blockIdx.y * 128, n0 = blockIdx.x * 128;

    // staging role: waves 0,1 -> A halves; waves 2,3 -> B halves
    const int isB = wave >> 1;
    const int half = wave & 1;
    const bf16_t* src = isB ? Bpk : Apk;
    const int tile0 = isB ? n0 : m0;
    const int lim = (isB ? N : M) - 1;
    const size_t rowBytes = (size_t)K * 4;  // packed row = 2K bf16 = 4K bytes

    uint32_t goff[9];
#pragma unroll
    for (int i = 0; i < 9; i++) {
        int s = i * 64 + lane;
        int rr = s / 9, cc = s % 9;
        if (cc == 8) cc = 0;  // pad chunk: load duplicate (harmless)
        int grow = tile0 + half * 64 + rr;
        if (grow > lim) grow = lim;
        goff[i] = (uint32_t)((size_t)grow * rowBytes + (size_t)cc * 16);
    }
    char* ldsWave = (char*)(isB ? Bs : As) + half * 9216;

    floatx4 acc[4][4];
#pragma unroll
    for (int i = 0; i < 4; i++)
#pragma unroll
        for (int j = 0; j < 4; j++)
#pragma unroll
            for (int p = 0; p < 4; p++) acc[i][j][p] = 0.f;

    for (int k0 = 0; k0 < K; k0 += 32) {
        __syncthreads();  // previous iter's fragment reads complete
        const char* gbase = (const char*)src + (size_t)k0 * 4;
#pragma unroll
        for (int i = 0; i < 9; i++) GLD(gbase + goff[i], ldsWave + i * 1024);
        __syncthreads();  // drains vmcnt -> staging visible

        bf16x8 ah[4], al[4], bh[4], bl[4];
#pragma unroll
        for (int i = 0; i < 4; i++) {
            const bf16_t* pa = &As[(wm + i * 16 + l16) * 72 + quad * 16];
            ah[i] = *(const bf16x8*)pa;
            al[i] = *(const bf16x8*)(pa + 8);
        }
#pragma unroll
        for (int j = 0; j < 4; j++) {
            const bf16_t* pb = &Bs[(wn + j * 16 + l16) * 72 + quad * 16];
            bh[j] = *(const bf16x8*)pb;
            bl[j] = *(const bf16x8*)(pb + 8);
        }
#pragma unroll
        for (int i = 0; i < 4; i++)
#pragma unroll
            for (int j = 0; j < 4; j++) {
                acc[i][j] = __builtin_amdgcn_mfma_f32_16x16x32_bf16(ah[i], bh[j], acc[i][j], 0, 0, 0);
                acc[i][j] = __builtin_amdgcn_mfma_f32_16x16x32_bf16(ah[i], bl[j], acc[i][j], 0, 0, 0);
                acc[i][j] = __builtin_amdgcn_mfma_f32_16x16x32_bf16(al[i], bh[j], acc[i][j], 0, 0, 0);
            }
    }

#pragma unroll
    for (int i = 0; i < 4; i++) {
#pragma unroll
        for (int p = 0; p < 4; p++) {
            int m = m0 + wm + i * 16 + quad * 4 + p;
            if (m >= M) continue;
            int pp = 0, row = m;
            if (mode == 4) { int b = m / 196; pp = m % 196; row = b * 197 + 1 + pp; }
#pragma unroll
            for (int j = 0; j < 4; j++) {
                int n = n0 + wn + j * 16 + l16;
                if (n >= N) continue;
                float v = acc[i][j][p] + bias[n];
                if (mode == 1) {
                    outF[(size_t)m * N + n] = v;
                } else if (mode == 2) {
                    float gl = 0.5f * v * (1.0f + erff(v * 0.70710678118654752f));
                    bf16_t h = f2b(gl);
                    size_t o = pk(m, n, N);
                    outP[o] = h;
                    outP[o + 8] = f2b(gl - b2f(h));
                } else if (mode == 3) {
                    outF[(size_t)m * N + n] += v;
                } else {  // mode 4
                    outF[(size_t)row * 768 + n] = v + pos[(size_t)(1 + pp) * 768 + n];
                }
            }
        }
    }
}

// ---------------- region sums of f32 LN output: hsum[208][768] ----------------
__global__ void regsum_kernel(const float* __restrict__ h, float* __restrict__ hsum) {
    int bid = blockIdx.x;  // b*13 + r
    int b = bid / 13, r = bid % 13;
    int t = threadIdx.x;
#pragma unroll
    for (int j = 0; j < 3; j++) {
        int c = t + j * 256;
        float s = 0.f;
        for (int tt = 0; tt < 16; tt++) {
            int tp = r * 16 + tt;
            if (tp < 197) s += h[((size_t)(b * 197 + tp)) * 768 + c];
        }
        hsum[(size_t)bid * 768 + c] = s;
    }
}

// ---------------- routing GEMM (f32): qreg/kreg = (hsum @ Wqk + n_r*b) / 16 ------
__global__ __launch_bounds__(256) void qkreg_gemm(const float* __restrict__ hsum,
                                                  const float* __restrict__ W,
                                                  const float* __restrict__ bias,
                                                  float* __restrict__ qreg,
                                                  float* __restrict__ kreg) {
    __shared__ float A_s[16][33];
    __shared__ float B_s[32][68];
    const int t = threadIdx.x;
    const int m0 = blockIdx.y * 16;
    const int n0 = blockIdx.x * 64;
    const int m = t >> 4;
    const int nn = (t & 15) * 4;
    floatx4 acc;
    acc[0] = acc[1] = acc[2] = acc[3] = 0.f;

    for (int k0 = 0; k0 < 768; k0 += 32) {
        {
            int c = (t & 15) * 2;
            A_s[t >> 4][c]     = hsum[(size_t)(m0 + (t >> 4)) * 768 + k0 + c];
            A_s[t >> 4][c + 1] = hsum[(size_t)(m0 + (t >> 4)) * 768 + k0 + c + 1];
        }
        {
            int kr = t >> 3, cc = (t & 7) * 8;
            const float* src = W + (size_t)(k0 + kr) * 2304 + n0 + cc;
            floatx4 w0 = *(const floatx4*)src;
            floatx4 w1 = *(const floatx4*)(src + 4);
            *(floatx4*)&B_s[kr][cc] = w0;
            *(floatx4*)&B_s[kr][cc + 4] = w1;
        }
        __syncthreads();
#pragma unroll
        for (int kk = 0; kk < 32; kk++) {
            float a = A_s[m][kk];
            floatx4 bv = *(const floatx4*)&B_s[kk][nn];
            acc += a * bv;
        }
        __syncthreads();
    }

    int row = m0 + m;
    int r = row % 13;
    float nr = (r == 12) ? 5.f : 16.f;
#pragma unroll
    for (int j = 0; j < 4; j++) {
        int c = n0 + nn + j;
        float val = (acc[j] + nr * bias[c]) * 0.0625f;
        if (c < 768) qreg[(size_t)row * 768 + c] = val;
        else         kreg[(size_t)row * 768 + (c - 768)] = val;
    }
}

// ---------------- affinity + top-4 fused: one block per (b,r) ----------------
__global__ __launch_bounds__(256) void afftopk_kernel(const float* __restrict__ qreg,
                                                      const float* __restrict__ kreg,
                                                      int* __restrict__ idx) {
    int bid = blockIdx.x;  // b*13 + r
    int b = bid / 13;
    int t = threadIdx.x;
    float q0 = qreg[(size_t)bid * 768 + t];
    float q1 = qreg[(size_t)bid * 768 + t + 256];
    float q2 = qreg[(size_t)bid * 768 + t + 512];
    __shared__ float red[4];
    __shared__ float affs[16];
    int lane = t & 63, wave = t >> 6;
    for (int s = 0; s < 13; s++) {
        const float* kp = kreg + ((size_t)(b * 13 + s)) * 768;
        float p = q0 * kp[t] + q1 * kp[t + 256] + q2 * kp[t + 512];
#pragma unroll
        for (int o = 32; o > 0; o >>= 1) p += __shfl_down(p, o, 64);
        if (lane == 0) red[wave] = p;
        __syncthreads();
        if (t == 0) affs[s] = red[0] + red[1] + red[2] + red[3];
        __syncthreads();
    }
    if (t == 0) {
        int mask = 0;
#pragma unroll
        for (int k = 0; k < 4; k++) {
            float best = -3.4e38f;
            int bi = 0;
            for (int s = 0; s < 13; s++)
                if (!((mask >> s) & 1) && affs[s] > best) { best = affs[s]; bi = s; }
            mask |= 1 << bi;
            idx[bid * 4 + k] = bi;
        }
    }
}

// ---------------- gathered attention per (b, region, head): f32 in, packed out ---
__global__ __launch_bounds__(256) void attn_kernel(const float* __restrict__ qkv,
                                                   const int* __restrict__ idx,
                                                   bf16_t* __restrict__ op) {
    __shared__ float q_s[16 * 65];
    __shared__ float K_s[64 * 65];
    __shared__ float V_s[64 * 65];
    __shared__ float P_s[16 * 65];
    int bid = blockIdx.x;
    int head = bid % 12;
    int r = (bid / 12) % 13;
    int b = bid / (12 * 13);
    int t = threadIdx.x;
    const int co = head * 64;

    int regs[4];
#pragma unroll
    for (int j = 0; j < 4; j++) regs[j] = idx[(b * 13 + r) * 4 + j];

#pragma unroll
    for (int i = 0; i < 4; i++) {
        int e = t + i * 256;
        int m = e >> 6, d = e & 63;
        int tp = r * 16 + m;
        q_s[m * 65 + d] = (tp < 197) ? qkv[((size_t)(b * 197 + tp)) * 2304 + co + d] : 0.f;
    }
#pragma unroll
    for (int i = 0; i < 16; i++) {
        int e = t + i * 256;
        int n = e >> 6, d = e & 63;
        int reg = regs[n >> 4];
        int tp = reg * 16 + (n & 15);
        float kv = 0.f, vv = 0.f;
        if (tp < 197) {
            size_t base = ((size_t)(b * 197 + tp)) * 2304;
            kv = qkv[base + 768 + co + d];
            vv = qkv[base + 1536 + co + d];
        }
        K_s[n * 65 + d] = kv;
        V_s[n * 65 + d] = vv;
    }
    __syncthreads();
    {
        int n = t & 63, mg = t >> 6;
#pragma unroll
        for (int i = 0; i < 4; i++) {
            int m = mg * 4 + i;
            float s = 0.f;
            for (int d = 0; d < 64; d++) s += q_s[m * 65 + d] * K_s[n * 65 + d];
            P_s[m * 65 + n] = s * 0.125f;
        }
    }
    __syncthreads();
    if (t < 16) {
        float mx = -3.4e38f;
        for (int n = 0; n < 64; n++) mx = fmaxf(mx, P_s[t * 65 + n]);
        float sum = 0.f;
        for (int n = 0; n < 64; n++) {
            float e = expf(P_s[t * 65 + n] - mx);
            P_s[t * 65 + n] = e;
            sum += e;
        }
        float inv = 1.f / sum;
        for (int n = 0; n < 64; n++) P_s[t * 65 + n] *= inv;
    }
    __syncthreads();
    {
        int d = t & 63, mg = t >> 6;
#pragma unroll
        for (int i = 0; i < 4; i++) {
            int m = mg * 4 + i;
            float o = 0.f;
            for (int n = 0; n < 64; n++) o += P_s[m * 65 + n] * V_s[n * 65 + d];
            int tp = r * 16 + m;
            if (tp < 197) {
                size_t oo = pk(b * 197 + tp, co + d, 768);
                bf16_t h = f2b(o);
                op[oo] = h;
                op[oo + 8] = f2b(o - b2f(h));
            }
        }
    }
}

// ---------------- extract t[:,0] packed for head GEMM ----------------
__global__ void headx_packed(const float* __restrict__ t, bf16_t* __restrict__ op) {
    int id = blockIdx.x * 256 + threadIdx.x;
    if (id >= 16 * 768) return;
    int b = id / 768, c = id % 768;
    float v = t[((size_t)(b * 197)) * 768 + c];
    bf16_t h = f2b(v);
    size_t o = pk(b, c, 768);
    op[o] = h;
    op[o + 8] = f2b(v - b2f(h));
}

extern "C" void kernel_launch(void* const* d_in, const int* in_sizes, int n_in,
                              void* d_out, int out_size, void* d_ws, size_t ws_size,
                              hipStream_t stream) {
    const float* x      = (const float*)d_in[0];
    const float* conv_w = (const float*)d_in[1];
    const float* conv_b = (const float*)d_in[2];
    const float* cls    = (const float*)d_in[3];
    const float* pos    = (const float*)d_in[4];
    const float* ln1g   = (const float*)d_in[5];
    const float* ln1b   = (const float*)d_in[6];
    const float* qkvw   = (const float*)d_in[7];
    const float* qkvb   = (const float*)d_in[8];
    const float* projw  = (const float*)d_in[9];
    const float* projb  = (const float*)d_in[10];
    const float* ln2g   = (const float*)d_in[11];
    const float* ln2b   = (const float*)d_in[12];
    const float* fc1w   = (const float*)d_in[13];
    const float* fc1b   = (const float*)d_in[14];
    const float* fc2w   = (const float*)d_in[15];
    const float* fc2b   = (const float*)d_in[16];
    const float* headw  = (const float*)d_in[17];
    const float* headb  = (const float*)d_in[18];
    float* out = (float*)d_out;

    char* ws = (char*)d_ws;
    size_t off = 0;
    auto alloc = [&](size_t bytes) -> void* {
        void* p = ws + off;
        off += (bytes + 255) & ~(size_t)255;
        return p;
    };
    float*  tbuf  = (float*)alloc((size_t)3152 * 768 * 4);
    float*  h32   = (float*)alloc((size_t)3152 * 768 * 4);
    bf16_t* lnP   = (bf16_t*)alloc((size_t)3152 * 1536 * 2);
    bf16_t* atP   = (bf16_t*)alloc((size_t)3152 * 1536 * 2);
    // union: geP (3152x6144 bf16) | qkvF (3152x2304 f32) | imP (3136x1536 bf16)
    char*   uni   = (char*)alloc((size_t)3152 * 6144 * 2);
    bf16_t* geP   = (bf16_t*)uni;
    float*  qkvF  = (float*)uni;
    bf16_t* imP   = (bf16_t*)uni;
    float*  hsum  = (float*)alloc((size_t)208 * 768 * 4);
    float*  qreg  = (float*)alloc((size_t)208 * 768 * 4);
    float*  kreg  = (float*)alloc((size_t)208 * 768 * 4);
    int*    idx   = (int*)alloc((size_t)832 * 4);
    bf16_t* convP = (bf16_t*)alloc((size_t)768 * 1536 * 2);
    bf16_t* headP = (bf16_t*)alloc((size_t)1000 * 1536 * 2);
    bf16_t* hdP   = (bf16_t*)alloc((size_t)16 * 1536 * 2);

    // weight-transpose area: batched (all 12 layers) if ws allows, else one slot
    const size_t qkvSz  = (size_t)2304 * 1536;  // elements (bf16)
    const size_t projSz = (size_t)768 * 1536;
    const size_t fc1Sz  = (size_t)3072 * 1536;
    const size_t fc2Sz  = (size_t)768 * 6144;
    size_t batchedBytes = 12 * (qkvSz + projSz + fc1Sz + fc2Sz) * 2;
    bool batched = (off + batchedBytes + 4096 <= ws_size);
    bf16_t *qkvP, *projP, *fc1P, *fc2P, *wslot = nullptr;
    if (batched) {
        qkvP  = (bf16_t*)alloc(12 * qkvSz * 2);
        projP = (bf16_t*)alloc(12 * projSz * 2);
        fc1P  = (bf16_t*)alloc(12 * fc1Sz * 2);
        fc2P  = (bf16_t*)alloc(12 * fc2Sz * 2);
    } else {
        wslot = (bf16_t*)alloc((size_t)3072 * 1536 * 2);  // max per-layer size
        qkvP = projP = fc1P = fc2P = wslot;
    }
    if (off > ws_size) return;  // guard

    dim3 blk(256);
    dim3 tblk(32, 8);

    // ---- one-time weight prep + patch embed ----
    im2col_packed<<<dim3(9408), blk, 0, stream>>>(x, imP);
    split_packed<<<dim3(2304), blk, 0, stream>>>(conv_w, convP, 768, 768);
    transpose_split_packed<<<dim3(32, 24, 1), tblk, 0, stream>>>(headw, headP, 768, 1000, 0, 0);
    if (batched) {
        transpose_split_packed<<<dim3(72, 24, 12), tblk, 0, stream>>>(
            qkvw, qkvP, 768, 2304, (size_t)768 * 2304, qkvSz);
        transpose_split_packed<<<dim3(24, 24, 12), tblk, 0, stream>>>(
            projw, projP, 768, 768, (size_t)768 * 768, projSz);
        transpose_split_packed<<<dim3(96, 24, 12), tblk, 0, stream>>>(
            fc1w, fc1P, 768, 3072, (size_t)768 * 3072, fc1Sz);
        transpose_split_packed<<<dim3(24, 96, 12), tblk, 0, stream>>>(
            fc2w, fc2P, 3072, 768, (size_t)3072 * 768, fc2Sz);
    }
    gemm_nts<<<dim3(6, 25), blk, 0, stream>>>(imP, convP, conv_b, tbuf, nullptr, pos,
                                              3136, 768, 768, 4);
    clspos_kernel<<<dim3(48), blk, 0, stream>>>(cls, pos, tbuf);

    for (int l = 0; l < 12; l++) {
        ln_kernel<<<dim3(3152), blk, 0, stream>>>(tbuf, ln1g + l * 768, ln1b + l * 768,
                                                  lnP, h32);

        // routing (f32 exact given state)
        regsum_kernel<<<dim3(208), blk, 0, stream>>>(h32, hsum);
        qkreg_gemm<<<dim3(24, 13), blk, 0, stream>>>(hsum, qkvw + (size_t)l * 768 * 2304,
                                                     qkvb + l * 2304, qreg, kreg);
        afftopk_kernel<<<dim3(208), blk, 0, stream>>>(qreg, kreg, idx);

        // qkv GEMM -> f32
        if (!batched)
            transpose_split_packed<<<dim3(72, 24, 1), tblk, 0, stream>>>(
                qkvw + (size_t)l * 768 * 2304, wslot, 768, 2304, 0, 0);
        gemm_nts<<<dim3(18, 25), blk, 0, stream>>>(lnP, qkvP + (batched ? l * qkvSz : 0),
                                                   qkvb + l * 2304, qkvF, nullptr, nullptr,
                                                   3152, 2304, 768, 1);

        attn_kernel<<<dim3(16 * 13 * 12), blk, 0, stream>>>(qkvF, idx, atP);

        if (!batched)
            transpose_split_packed<<<dim3(24, 24, 1), tblk, 0, stream>>>(
                projw + (size_t)l * 768 * 768, wslot, 768, 768, 0, 0);
        gemm_nts<<<dim3(6, 25), blk, 0, stream>>>(atP, projP + (batched ? l * projSz : 0),
                                                  projb + l * 768, h32, nullptr, nullptr,
                                                  3152, 768, 768, 1);

        ln_kernel<<<dim3(3152), blk, 0, stream>>>(h32, ln2g + l * 768, ln2b + l * 768,
                                                  lnP, (float*)nullptr);

        if (!batched)
            transpose_split_packed<<<dim3(96, 24, 1), tblk, 0, stream>>>(
                fc1w + (size_t)l * 768 * 3072, wslot, 768, 3072, 0, 0);
        gemm_nts<<<dim3(24, 25), blk, 0, stream>>>(lnP, fc1P + (batched ? l * fc1Sz : 0),
                                                   fc1b + l * 3072, nullptr, geP, nullptr,
                                                   3152, 3072, 768, 2);

        if (!batched)
            transpose_split_packed<<<dim3(24, 96, 1), tblk, 0, stream>>>(
                fc2w + (size_t)l * 3072 * 768, wslot, 3072, 768, 0, 0);
        gemm_nts<<<dim3(6, 25), blk, 0, stream>>>(geP, fc2P + (batched ? l * fc2Sz : 0),
                                                  fc2b + l * 768, tbuf, nullptr, nullptr,
                                                  3152, 768, 3072, 3);
    }

    // ---- classification head ----
    headx_packed<<<dim3(48), blk, 0, stream>>>(tbuf, hdP);
    gemm_nts<<<dim3(8, 1), blk, 0, stream>>>(hdP, headP, headb, out, nullptr, nullptr,
                                             16, 1000, 768, 1);
}